// Round 1
// baseline (3322.383 us; speedup 1.0000x reference)
//
#include <hip/hip_runtime.h>

#define NN 100000
#define NE 1600000
#define HD 128
#define EPSV 1e-8f

__device__ __forceinline__ float silu_f(float x) {
    return x / (1.0f + __expf(-x));
}
__device__ __forceinline__ float b2f(unsigned short u) {
    union { unsigned int i; float f; } v; v.i = ((unsigned int)u) << 16; return v.f;
}
__device__ __forceinline__ unsigned short f2b(float f) {
    union { float f; unsigned int i; } v; v.f = f;
    unsigned int r = v.i + 0x7fff + ((v.i >> 16) & 1);
    return (unsigned short)(r >> 16);
}

// ---------------------------------------------------------------------------
// Kernel 1: A[n] = h[n] @ We1[0:128,:] + be1 ; B[n] = h[n] @ We1[128:256,:]
// 16 nodes per 256-thread block; thread (j = tid&127, mat = tid>>7).
// ---------------------------------------------------------------------------
extern "C" __global__ __launch_bounds__(256)
void k_nodeAB(const float* __restrict__ h, const float* __restrict__ We1,
              const float* __restrict__ be1, float* __restrict__ A,
              float* __restrict__ B)
{
    __shared__ float hs[16][HD];
    const int tid = threadIdx.x;
    const int j = tid & 127;
    const int mat = tid >> 7;
    const int n0 = blockIdx.x * 16;
    for (int i = tid; i < 16 * HD; i += 256) {
        hs[i >> 7][i & 127] = h[(size_t)(n0 + (i >> 7)) * HD + (i & 127)];
    }
    __syncthreads();
    float acc[16];
#pragma unroll
    for (int ni = 0; ni < 16; ni++) acc[ni] = 0.f;
    const float* W = We1 + (size_t)mat * HD * HD + j;
    for (int k4 = 0; k4 < 32; k4++) {
        float w0 = W[(size_t)(4 * k4 + 0) * HD];
        float w1 = W[(size_t)(4 * k4 + 1) * HD];
        float w2 = W[(size_t)(4 * k4 + 2) * HD];
        float w3 = W[(size_t)(4 * k4 + 3) * HD];
#pragma unroll
        for (int ni = 0; ni < 16; ni++) {
            float4 hv = *(const float4*)&hs[ni][4 * k4];
            acc[ni] += hv.x * w0 + hv.y * w1 + hv.z * w2 + hv.w * w3;
        }
    }
    float bias = (mat == 0) ? be1[j] : 0.f;
    float* dst = (mat == 0) ? A : B;
#pragma unroll
    for (int ni = 0; ni < 16; ni++) {
        dst[(size_t)(n0 + ni) * HD + j] = acc[ni] + bias;
    }
}

// ---------------------------------------------------------------------------
// Kernel 2: edge kernel — one edge per thread (256 edges / block).
// m1 = silu(A[row]+B[col]+radial*WeL); m = silu(m1@We2+be2)  (acc[128] VGPR,
// weights wave-uniform -> SMEM). m -> bf16 LDS (padded) for the coord head
// and a coalesced transposed atomic scatter of agg_h.
// ---------------------------------------------------------------------------
extern "C" __global__ __launch_bounds__(256)
void k_edge(const int* __restrict__ ei, const float* __restrict__ coord,
            const float* __restrict__ A, const float* __restrict__ B,
            const float* __restrict__ We1,
            const float* __restrict__ We2, const float* __restrict__ be2,
            const float* __restrict__ Wc1, const float* __restrict__ bc1,
            const float* __restrict__ Wc2,
            float* __restrict__ agg_h, float* __restrict__ agg_c,
            float* __restrict__ cnt)
{
    __shared__ unsigned short m_lds[HD][257];  // [k][edge-slot], padded stride
    __shared__ int rows_s[256];
    const int tid = threadIdx.x;
    const int e = blockIdx.x * 256 + tid;
    const int row = ei[e];
    const int col = ei[NE + e];
    rows_s[tid] = row;

    float c0 = coord[(size_t)row * 3 + 0] - coord[(size_t)col * 3 + 0];
    float c1 = coord[(size_t)row * 3 + 1] - coord[(size_t)col * 3 + 1];
    float c2 = coord[(size_t)row * 3 + 2] - coord[(size_t)col * 3 + 2];
    float radial = c0 * c0 + c1 * c1 + c2 * c2;

    const float4* A4 = (const float4*)(A + (size_t)row * HD);
    const float4* B4 = (const float4*)(B + (size_t)col * HD);
    const float4* WL4 = (const float4*)(We1 + (size_t)256 * HD);

    float acc[HD];
#pragma unroll
    for (int jj = 0; jj < HD; jj++) acc[jj] = be2[jj];

    for (int k4 = 0; k4 < 32; k4++) {
        float4 av = A4[k4];
        float4 bv = B4[k4];
        float4 wl = WL4[k4];
        float m10 = silu_f(av.x + bv.x + radial * wl.x);
        float m11 = silu_f(av.y + bv.y + radial * wl.y);
        float m12 = silu_f(av.z + bv.z + radial * wl.z);
        float m13 = silu_f(av.w + bv.w + radial * wl.w);
        const float* w0 = We2 + (size_t)(4 * k4 + 0) * HD;
        const float* w1 = We2 + (size_t)(4 * k4 + 1) * HD;
        const float* w2 = We2 + (size_t)(4 * k4 + 2) * HD;
        const float* w3 = We2 + (size_t)(4 * k4 + 3) * HD;
#pragma unroll
        for (int jj = 0; jj < HD; jj++) {
            acc[jj] += m10 * w0[jj] + m11 * w1[jj] + m12 * w2[jj] + m13 * w3[jj];
        }
    }
    // m = silu(acc) -> LDS (own column), bf16
#pragma unroll
    for (int jj = 0; jj < HD; jj++) {
        m_lds[jj][tid] = f2b(silu_f(acc[jj]));
    }

    // coord head: phi = sum_j silu(bc1[j] + sum_k m[k]*Wc1[k][j]) * Wc2[j]
    float phi = 0.f;
    for (int jc = 0; jc < 4; jc++) {
        float q[32];
#pragma unroll
        for (int jj = 0; jj < 32; jj++) q[jj] = bc1[jc * 32 + jj];
        for (int k = 0; k < HD; k++) {
            float mk = b2f(m_lds[k][tid]);
            const float* wr = Wc1 + (size_t)k * HD + jc * 32;
#pragma unroll
            for (int jj = 0; jj < 32; jj++) q[jj] += mk * wr[jj];
        }
#pragma unroll
        for (int jj = 0; jj < 32; jj++) phi += silu_f(q[jj]) * Wc2[jc * 32 + jj];
    }

    float inv = 1.0f / (sqrtf(radial) + EPSV);
    atomicAdd(&agg_c[(size_t)row * 3 + 0], c0 * inv * phi);
    atomicAdd(&agg_c[(size_t)row * 3 + 1], c1 * inv * phi);
    atomicAdd(&agg_c[(size_t)row * 3 + 2], c2 * inv * phi);
    atomicAdd(&cnt[row], 1.0f);

    __syncthreads();
    // coalesced scatter of m into agg_h: 2 edges per iteration, 128 lanes each
    const int g = tid >> 7;
    const int j = tid & 127;
    for (int eb = 0; eb < 128; eb++) {
        int es = eb * 2 + g;
        float mv = b2f(m_lds[j][es]);
        atomicAdd(&agg_h[(size_t)rows_s[es] * HD + j], mv);
    }
}

// ---------------------------------------------------------------------------
// Kernel 3: node kernel — one node per thread.
// out = silu([h|agg_h]@Wn1+bn1)@Wn2+bn2 ; h_out = h+out ; coord fixup.
// agg_h lives in d_out[0:N*128] and is overwritten with h_out in place.
// ---------------------------------------------------------------------------
extern "C" __global__ __launch_bounds__(256)
void k_node(const float* __restrict__ h, const float* __restrict__ Wn1,
            const float* __restrict__ bn1, const float* __restrict__ Wn2,
            const float* __restrict__ bn2, const float* __restrict__ coord,
            const float* __restrict__ cnt,
            float* __restrict__ hout /* = agg_h in */,
            float* __restrict__ cout /* = agg_c in */)
{
    __shared__ unsigned short u_lds[HD][257];
    const int tid = threadIdx.x;
    const int n = blockIdx.x * 256 + tid;
    if (n >= NN) return;  // no barriers below -> safe

    float acc[HD];
#pragma unroll
    for (int jj = 0; jj < HD; jj++) acc[jj] = bn1[jj];

    const float4* H4 = (const float4*)(h + (size_t)n * HD);
    const float4* G4 = (const float4*)(hout + (size_t)n * HD);
    for (int k4 = 0; k4 < 32; k4++) {
        float4 hv = H4[k4];
        const float* w0 = Wn1 + (size_t)(4 * k4 + 0) * HD;
        const float* w1 = Wn1 + (size_t)(4 * k4 + 1) * HD;
        const float* w2 = Wn1 + (size_t)(4 * k4 + 2) * HD;
        const float* w3 = Wn1 + (size_t)(4 * k4 + 3) * HD;
#pragma unroll
        for (int jj = 0; jj < HD; jj++) {
            acc[jj] += hv.x * w0[jj] + hv.y * w1[jj] + hv.z * w2[jj] + hv.w * w3[jj];
        }
    }
    for (int k4 = 0; k4 < 32; k4++) {
        float4 gv = G4[k4];
        const float* w0 = Wn1 + (size_t)(HD + 4 * k4 + 0) * HD;
        const float* w1 = Wn1 + (size_t)(HD + 4 * k4 + 1) * HD;
        const float* w2 = Wn1 + (size_t)(HD + 4 * k4 + 2) * HD;
        const float* w3 = Wn1 + (size_t)(HD + 4 * k4 + 3) * HD;
#pragma unroll
        for (int jj = 0; jj < HD; jj++) {
            acc[jj] += gv.x * w0[jj] + gv.y * w1[jj] + gv.z * w2[jj] + gv.w * w3[jj];
        }
    }
#pragma unroll
    for (int jj = 0; jj < HD; jj++) u_lds[jj][tid] = f2b(silu_f(acc[jj]));

    for (int jc = 0; jc < 4; jc++) {
        float o[32];
#pragma unroll
        for (int jj = 0; jj < 32; jj++) o[jj] = bn2[jc * 32 + jj];
        for (int k = 0; k < HD; k++) {
            float uk = b2f(u_lds[k][tid]);
            const float* wr = Wn2 + (size_t)k * HD + jc * 32;
#pragma unroll
            for (int jj = 0; jj < 32; jj++) o[jj] += uk * wr[jj];
        }
#pragma unroll
        for (int jj = 0; jj < 32; jj++) {
            size_t idx = (size_t)n * HD + jc * 32 + jj;
            hout[idx] = h[idx] + o[jj];
        }
    }

    float c = cnt[n];
    float invc = 1.0f / fmaxf(c, 1.0f);
#pragma unroll
    for (int i = 0; i < 3; i++) {
        size_t idx = (size_t)n * 3 + i;
        cout[idx] = coord[idx] + cout[idx] * invc;
    }
}

// ---------------------------------------------------------------------------
extern "C" void kernel_launch(void* const* d_in, const int* in_sizes, int n_in,
                              void* d_out, int out_size, void* d_ws, size_t ws_size,
                              hipStream_t stream)
{
    const float* h     = (const float*)d_in[0];
    const int*   ei    = (const int*)d_in[1];
    const float* coord = (const float*)d_in[2];
    const float* We1   = (const float*)d_in[3];
    const float* be1   = (const float*)d_in[4];
    const float* We2   = (const float*)d_in[5];
    const float* be2   = (const float*)d_in[6];
    const float* Wn1   = (const float*)d_in[7];
    const float* bn1   = (const float*)d_in[8];
    const float* Wn2   = (const float*)d_in[9];
    const float* bn2   = (const float*)d_in[10];
    const float* Wc1   = (const float*)d_in[11];
    const float* bc1   = (const float*)d_in[12];
    const float* Wc2   = (const float*)d_in[13];

    float* out   = (float*)d_out;
    float* agg_h = out;                         // [NN,128] accum, then h_out
    float* agg_c = out + (size_t)NN * HD;       // [NN,3]  accum, then coord_out
    float* A   = (float*)d_ws;                  // [NN,128]
    float* B   = A + (size_t)NN * HD;           // [NN,128]
    float* cnt = B + (size_t)NN * HD;           // [NN]

    hipMemsetAsync(d_out, 0, (size_t)out_size * sizeof(float), stream);
    hipMemsetAsync(cnt, 0, (size_t)NN * sizeof(float), stream);

    k_nodeAB<<<NN / 16, 256, 0, stream>>>(h, We1, be1, A, B);
    k_edge<<<NE / 256, 256, 0, stream>>>(ei, coord, A, B, We1, We2, be2,
                                         Wc1, bc1, Wc2, agg_h, agg_c, cnt);
    k_node<<<(NN + 255) / 256, 256, 0, stream>>>(h, Wn1, bn1, Wn2, bn2, coord,
                                                 cnt, agg_h, agg_c);
}

// Round 2
// 1482.249 us; speedup vs baseline: 2.2414x; 2.2414x over previous
//
#include <hip/hip_runtime.h>

#define NN 100000
#define NE 1600000
#define HD 128
#define EPSV 1e-8f
#define EB 128      // edges per block in k_edge
#define LPAD 136    // padded LDS row length (bf16 elems): 272 B, 16B-aligned

typedef __attribute__((ext_vector_type(8))) short bf16x8;
typedef __attribute__((ext_vector_type(4))) float f32x4;

__device__ __forceinline__ float silu_f(float x) {
    return x / (1.0f + __expf(-x));
}
__device__ __forceinline__ float b2f(unsigned short u) {
    union { unsigned int i; float f; } v; v.i = ((unsigned int)u) << 16; return v.f;
}
__device__ __forceinline__ unsigned short f2b(float f) {
    union { float f; unsigned int i; } v; v.f = f;
    unsigned int r = v.i + 0x7fff + ((v.i >> 16) & 1);
    return (unsigned short)(r >> 16);
}

// ---------------------------------------------------------------------------
// Kernel 0: transpose We2, Wc1 to bf16 [n][k] layout for MFMA B-operand.
// ---------------------------------------------------------------------------
extern "C" __global__ __launch_bounds__(256)
void k_prep(const float* __restrict__ We2, const float* __restrict__ Wc1,
            unsigned short* __restrict__ We2T, unsigned short* __restrict__ Wc1T)
{
    int id = blockIdx.x * 256 + threadIdx.x;
    if (id >= 2 * HD * HD) return;
    int mat = id >> 14;
    int r = id & 16383;
    int n = r >> 7, k = r & 127;
    const float* src = mat ? Wc1 : We2;
    unsigned short* dst = mat ? Wc1T : We2T;
    dst[r] = f2b(src[k * HD + n]);
}

// ---------------------------------------------------------------------------
// Kernel 1: A[n] = h[n] @ We1[0:128,:] + be1 ; B[n] = h[n] @ We1[128:256,:]
// ---------------------------------------------------------------------------
extern "C" __global__ __launch_bounds__(256)
void k_nodeAB(const float* __restrict__ h, const float* __restrict__ We1,
              const float* __restrict__ be1, float* __restrict__ A,
              float* __restrict__ B)
{
    __shared__ float hs[16][HD];
    const int tid = threadIdx.x;
    const int j = tid & 127;
    const int mat = tid >> 7;
    const int n0 = blockIdx.x * 16;
    for (int i = tid; i < 16 * HD; i += 256) {
        hs[i >> 7][i & 127] = h[(size_t)(n0 + (i >> 7)) * HD + (i & 127)];
    }
    __syncthreads();
    float acc[16];
#pragma unroll
    for (int ni = 0; ni < 16; ni++) acc[ni] = 0.f;
    const float* W = We1 + (size_t)mat * HD * HD + j;
    for (int k4 = 0; k4 < 32; k4++) {
        float w0 = W[(size_t)(4 * k4 + 0) * HD];
        float w1 = W[(size_t)(4 * k4 + 1) * HD];
        float w2 = W[(size_t)(4 * k4 + 2) * HD];
        float w3 = W[(size_t)(4 * k4 + 3) * HD];
#pragma unroll
        for (int ni = 0; ni < 16; ni++) {
            float4 hv = *(const float4*)&hs[ni][4 * k4];
            acc[ni] += hv.x * w0 + hv.y * w1 + hv.z * w2 + hv.w * w3;
        }
    }
    float bias = (mat == 0) ? be1[j] : 0.f;
    float* dst = (mat == 0) ? A : B;
#pragma unroll
    for (int ni = 0; ni < 16; ni++) {
        dst[(size_t)(n0 + ni) * HD + j] = acc[ni] + bias;
    }
}

// ---------------------------------------------------------------------------
// Kernel 2: MFMA edge kernel. 128 edges / 256 threads / 4 waves per block.
//   m1 = silu(A[row]+B[col]+radial*WeL)      (fp32 VALU -> bf16 LDS)
//   m  = silu(m1 @ We2 + be2)                 (MFMA GEMM1)
//   phi = silu(m @ Wc1 + bc1) @ Wc2           (MFMA GEMM2 + shfl reduce)
//   atomics: agg_c (4 lanes/wave), agg_h (coalesced transposed scatter)
// ---------------------------------------------------------------------------
extern "C" __global__ __launch_bounds__(256)
void k_edge(const int* __restrict__ ei, const float* __restrict__ coord,
            const float* __restrict__ A, const float* __restrict__ B,
            const float* __restrict__ We1, const float* __restrict__ be2,
            const unsigned short* __restrict__ We2T,
            const unsigned short* __restrict__ Wc1T,
            const float* __restrict__ bc1, const float* __restrict__ Wc2,
            float* __restrict__ agg_h, float* __restrict__ agg_c,
            float* __restrict__ cnt)
{
    __shared__ unsigned short m_lds[EB][LPAD];   // m1, then m (bf16)
    __shared__ unsigned short w_lds[HD][LPAD];   // We2T, then Wc1T (bf16)
    __shared__ float cd_lds[EB][4];              // normalized coord diff
    __shared__ int rows_s[EB];

    const int tid = threadIdx.x;
    const int e  = tid >> 1;       // edge slot 0..127
    const int hf = tid & 1;        // feature half
    const int ge = blockIdx.x * EB + e;
    const int row = ei[ge];
    const int col = ei[NE + ge];

    // ---- phase 0: coord/radial, m1 -> LDS, weights -> LDS ----
    float c0 = coord[(size_t)row * 3 + 0] - coord[(size_t)col * 3 + 0];
    float c1 = coord[(size_t)row * 3 + 1] - coord[(size_t)col * 3 + 1];
    float c2 = coord[(size_t)row * 3 + 2] - coord[(size_t)col * 3 + 2];
    float radial = c0 * c0 + c1 * c1 + c2 * c2;
    if (hf == 0) {
        rows_s[e] = row;
        float inv = 1.0f / (sqrtf(radial) + EPSV);
        cd_lds[e][0] = c0 * inv; cd_lds[e][1] = c1 * inv; cd_lds[e][2] = c2 * inv;
    }

    {
        const float4* A4  = (const float4*)(A + (size_t)row * HD) + hf * 16;
        const float4* B4  = (const float4*)(B + (size_t)col * HD) + hf * 16;
        const float4* WL4 = (const float4*)(We1 + (size_t)2 * HD * HD) + hf * 16;
#pragma unroll
        for (int i = 0; i < 16; i += 2) {
            float4 a0 = A4[i],     b0 = B4[i],     w0 = WL4[i];
            float4 a1 = A4[i + 1], b1 = B4[i + 1], w1 = WL4[i + 1];
            bf16x8 pk;
            pk[0] = (short)f2b(silu_f(a0.x + b0.x + radial * w0.x));
            pk[1] = (short)f2b(silu_f(a0.y + b0.y + radial * w0.y));
            pk[2] = (short)f2b(silu_f(a0.z + b0.z + radial * w0.z));
            pk[3] = (short)f2b(silu_f(a0.w + b0.w + radial * w0.w));
            pk[4] = (short)f2b(silu_f(a1.x + b1.x + radial * w1.x));
            pk[5] = (short)f2b(silu_f(a1.y + b1.y + radial * w1.y));
            pk[6] = (short)f2b(silu_f(a1.z + b1.z + radial * w1.z));
            pk[7] = (short)f2b(silu_f(a1.w + b1.w + radial * w1.w));
            *(bf16x8*)&m_lds[e][hf * 64 + i * 4] = pk;
        }
    }
    {   // We2T -> w_lds  (thread t: row t>>1, half t&1)
        const int wr = tid >> 1, wh = tid & 1;
        const bf16x8* src = (const bf16x8*)(We2T + wr * HD + wh * 64);
        bf16x8* dst = (bf16x8*)&w_lds[wr][wh * 64];
#pragma unroll
        for (int i = 0; i < 8; i++) dst[i] = src[i];
    }
    __syncthreads();

    // ---- GEMM1: m1[128x128] @ We2 -> acc ----
    const int wave = tid >> 6, lane = tid & 63;
    const int lr = lane & 15, lg = lane >> 4;
    float be2v[8], bc1v[8], wc2v[8];
#pragma unroll
    for (int nt = 0; nt < 8; nt++) {
        be2v[nt] = be2[nt * 16 + lr];
        bc1v[nt] = bc1[nt * 16 + lr];
        wc2v[nt] = Wc2[nt * 16 + lr];
    }

    f32x4 acc[2][8];
#pragma unroll
    for (int mt = 0; mt < 2; mt++)
#pragma unroll
        for (int nt = 0; nt < 8; nt++) acc[mt][nt] = (f32x4){0.f, 0.f, 0.f, 0.f};

#pragma unroll
    for (int ks = 0; ks < 4; ks++) {
        bf16x8 af[2], bfr[8];
#pragma unroll
        for (int mt = 0; mt < 2; mt++)
            af[mt] = *(const bf16x8*)&m_lds[wave * 32 + mt * 16 + lr][ks * 32 + lg * 8];
#pragma unroll
        for (int nt = 0; nt < 8; nt++)
            bfr[nt] = *(const bf16x8*)&w_lds[nt * 16 + lr][ks * 32 + lg * 8];
#pragma unroll
        for (int mt = 0; mt < 2; mt++)
#pragma unroll
            for (int nt = 0; nt < 8; nt++)
                acc[mt][nt] = __builtin_amdgcn_mfma_f32_16x16x32_bf16(
                    af[mt], bfr[nt], acc[mt][nt], 0, 0, 0);
    }

    // m = silu(acc + be2) -> back into m_lds (own wave's 32 rows only)
#pragma unroll
    for (int mt = 0; mt < 2; mt++)
#pragma unroll
        for (int r = 0; r < 4; r++) {
            int rrow = wave * 32 + mt * 16 + lg * 4 + r;
#pragma unroll
            for (int nt = 0; nt < 8; nt++)
                m_lds[rrow][nt * 16 + lr] = f2b(silu_f(acc[mt][nt][r] + be2v[nt]));
        }
    __syncthreads();   // all GEMM1 w_lds reads + m writes done

    {   // Wc1T -> w_lds
        const int wr = tid >> 1, wh = tid & 1;
        const bf16x8* src = (const bf16x8*)(Wc1T + wr * HD + wh * 64);
        bf16x8* dst = (bf16x8*)&w_lds[wr][wh * 64];
#pragma unroll
        for (int i = 0; i < 8; i++) dst[i] = src[i];
    }
    __syncthreads();

    // ---- GEMM2: m[128x128] @ Wc1 -> acc ----
#pragma unroll
    for (int mt = 0; mt < 2; mt++)
#pragma unroll
        for (int nt = 0; nt < 8; nt++) acc[mt][nt] = (f32x4){0.f, 0.f, 0.f, 0.f};

#pragma unroll
    for (int ks = 0; ks < 4; ks++) {
        bf16x8 af[2], bfr[8];
#pragma unroll
        for (int mt = 0; mt < 2; mt++)
            af[mt] = *(const bf16x8*)&m_lds[wave * 32 + mt * 16 + lr][ks * 32 + lg * 8];
#pragma unroll
        for (int nt = 0; nt < 8; nt++)
            bfr[nt] = *(const bf16x8*)&w_lds[nt * 16 + lr][ks * 32 + lg * 8];
#pragma unroll
        for (int mt = 0; mt < 2; mt++)
#pragma unroll
            for (int nt = 0; nt < 8; nt++)
                acc[mt][nt] = __builtin_amdgcn_mfma_f32_16x16x32_bf16(
                    af[mt], bfr[nt], acc[mt][nt], 0, 0, 0);
    }

    // phi = sum_j silu(u + bc1) * Wc2, reduced across the 16 col-lanes
    float ph[2][4];
#pragma unroll
    for (int mt = 0; mt < 2; mt++)
#pragma unroll
        for (int r = 0; r < 4; r++) ph[mt][r] = 0.f;
#pragma unroll
    for (int mt = 0; mt < 2; mt++)
#pragma unroll
        for (int nt = 0; nt < 8; nt++)
#pragma unroll
            for (int r = 0; r < 4; r++)
                ph[mt][r] += silu_f(acc[mt][nt][r] + bc1v[nt]) * wc2v[nt];
#pragma unroll
    for (int msk = 1; msk < 16; msk <<= 1)
#pragma unroll
        for (int mt = 0; mt < 2; mt++)
#pragma unroll
            for (int r = 0; r < 4; r++)
                ph[mt][r] += __shfl_xor(ph[mt][r], msk, 64);

    if (lr == 0) {
#pragma unroll
        for (int mt = 0; mt < 2; mt++)
#pragma unroll
            for (int r = 0; r < 4; r++) {
                int er = wave * 32 + mt * 16 + lg * 4 + r;
                int ro = rows_s[er];
                float p = ph[mt][r];
                atomicAdd(&agg_c[(size_t)ro * 3 + 0], cd_lds[er][0] * p);
                atomicAdd(&agg_c[(size_t)ro * 3 + 1], cd_lds[er][1] * p);
                atomicAdd(&agg_c[(size_t)ro * 3 + 2], cd_lds[er][2] * p);
                atomicAdd(&cnt[ro], 1.0f);
            }
    }

    // ---- agg_h scatter: coalesced, 128 lanes cover one edge row ----
    {
        const int j = tid & 127, g = tid >> 7;
        for (int eb = 0; eb < 64; eb++) {
            int es = eb * 2 + g;
            atomicAdd(&agg_h[(size_t)rows_s[es] * HD + j], b2f(m_lds[es][j]));
        }
    }
}

// ---------------------------------------------------------------------------
// Kernel 3: node MLP, one node per thread, j chunked 2x64 (no spills).
// ---------------------------------------------------------------------------
extern "C" __global__ __launch_bounds__(256)
void k_node(const float* __restrict__ h, const float* __restrict__ Wn1,
            const float* __restrict__ bn1, const float* __restrict__ Wn2,
            const float* __restrict__ bn2, const float* __restrict__ coord,
            const float* __restrict__ cnt,
            float* __restrict__ hout /* = agg_h in */,
            float* __restrict__ cout /* = agg_c in */)
{
    __shared__ unsigned short u_lds[HD][257];
    const int tid = threadIdx.x;
    const int n = blockIdx.x * 256 + tid;
    if (n >= NN) return;  // no barriers below -> safe

    const float4* H4 = (const float4*)(h + (size_t)n * HD);
    const float4* G4 = (const float4*)(hout + (size_t)n * HD);

    for (int half = 0; half < 2; half++) {
        float acc[64];
#pragma unroll
        for (int j = 0; j < 64; j++) acc[j] = bn1[half * 64 + j];
        for (int k4 = 0; k4 < 32; k4++) {
            float4 hv = H4[k4];
            const float* w0 = Wn1 + (size_t)(4 * k4 + 0) * HD + half * 64;
            const float* w1 = Wn1 + (size_t)(4 * k4 + 1) * HD + half * 64;
            const float* w2 = Wn1 + (size_t)(4 * k4 + 2) * HD + half * 64;
            const float* w3 = Wn1 + (size_t)(4 * k4 + 3) * HD + half * 64;
#pragma unroll
            for (int j = 0; j < 64; j++)
                acc[j] += hv.x * w0[j] + hv.y * w1[j] + hv.z * w2[j] + hv.w * w3[j];
        }
        for (int k4 = 0; k4 < 32; k4++) {
            float4 gv = G4[k4];
            const float* w0 = Wn1 + (size_t)(HD + 4 * k4 + 0) * HD + half * 64;
            const float* w1 = Wn1 + (size_t)(HD + 4 * k4 + 1) * HD + half * 64;
            const float* w2 = Wn1 + (size_t)(HD + 4 * k4 + 2) * HD + half * 64;
            const float* w3 = Wn1 + (size_t)(HD + 4 * k4 + 3) * HD + half * 64;
#pragma unroll
            for (int j = 0; j < 64; j++)
                acc[j] += gv.x * w0[j] + gv.y * w1[j] + gv.z * w2[j] + gv.w * w3[j];
        }
#pragma unroll
        for (int j = 0; j < 64; j++)
            u_lds[half * 64 + j][tid] = f2b(silu_f(acc[j]));
    }

    for (int jc = 0; jc < 4; jc++) {
        float o[32];
#pragma unroll
        for (int jj = 0; jj < 32; jj++) o[jj] = bn2[jc * 32 + jj];
        for (int k = 0; k < HD; k++) {
            float uk = b2f(u_lds[k][tid]);
            const float* wr = Wn2 + (size_t)k * HD + jc * 32;
#pragma unroll
            for (int jj = 0; jj < 32; jj++) o[jj] += uk * wr[jj];
        }
#pragma unroll
        for (int jj = 0; jj < 32; jj++) {
            size_t idx = (size_t)n * HD + jc * 32 + jj;
            hout[idx] = h[idx] + o[jj];
        }
    }

    float invc = 1.0f / fmaxf(cnt[n], 1.0f);
#pragma unroll
    for (int i = 0; i < 3; i++) {
        size_t idx = (size_t)n * 3 + i;
        cout[idx] = coord[idx] + cout[idx] * invc;
    }
}

// ---------------------------------------------------------------------------
extern "C" void kernel_launch(void* const* d_in, const int* in_sizes, int n_in,
                              void* d_out, int out_size, void* d_ws, size_t ws_size,
                              hipStream_t stream)
{
    const float* h     = (const float*)d_in[0];
    const int*   ei    = (const int*)d_in[1];
    const float* coord = (const float*)d_in[2];
    const float* We1   = (const float*)d_in[3];
    const float* be1   = (const float*)d_in[4];
    const float* We2   = (const float*)d_in[5];
    const float* be2   = (const float*)d_in[6];
    const float* Wn1   = (const float*)d_in[7];
    const float* bn1   = (const float*)d_in[8];
    const float* Wn2   = (const float*)d_in[9];
    const float* bn2   = (const float*)d_in[10];
    const float* Wc1   = (const float*)d_in[11];
    const float* bc1   = (const float*)d_in[12];
    const float* Wc2   = (const float*)d_in[13];

    float* out   = (float*)d_out;
    float* agg_h = out;                         // [NN,128] accum, then h_out
    float* agg_c = out + (size_t)NN * HD;       // [NN,3]  accum, then coord_out
    float* A   = (float*)d_ws;                  // [NN,128] fp32
    float* B   = A + (size_t)NN * HD;           // [NN,128] fp32
    float* cnt = B + (size_t)NN * HD;           // [NN] fp32
    unsigned short* We2T = (unsigned short*)(cnt + NN);  // [128,128] bf16 (16B-aligned)
    unsigned short* Wc1T = We2T + HD * HD;               // [128,128] bf16

    hipMemsetAsync(d_out, 0, (size_t)out_size * sizeof(float), stream);
    hipMemsetAsync(cnt, 0, (size_t)NN * sizeof(float), stream);

    k_prep<<<(2 * HD * HD + 255) / 256, 256, 0, stream>>>(We2, Wc1, We2T, Wc1T);
    k_nodeAB<<<NN / 16, 256, 0, stream>>>(h, We1, be1, A, B);
    k_edge<<<NE / EB, 256, 0, stream>>>(ei, coord, A, B, We1, be2,
                                        We2T, Wc1T, bc1, Wc2, agg_h, agg_c, cnt);
    k_node<<<(NN + 255) / 256, 256, 0, stream>>>(h, Wn1, bn1, Wn2, bn2, coord,
                                                 cnt, agg_h, agg_c);
}